// Round 6
// baseline (120.264 us; speedup 1.0000x reference)
//
#include <hip/hip_runtime.h>

#define NLOC 384

// ws layout: ab[384*64] f32 at byte 0 (96 KB); T[384*32*64] f32 at byte 98304 (3 MB).
// T[j][x*64+p] = sum_y b[j][y] * W_out[p][x*32+y],  b[j][y] = ab[j*64+32+y]

// ab[n][h] = (sum_d m[n,d] * W_in[h,d] + b_in[h]) * op_mask    grid=96
__global__ __launch_bounds__(256) void k_ab(const float* __restrict__ m,
                                            const float* __restrict__ W_in,
                                            const float* __restrict__ b_in,
                                            const float* __restrict__ op_mask,
                                            float* __restrict__ ab) {
    const int t  = threadIdx.x;
    const int h  = t & 63;
    const int ng = __builtin_amdgcn_readfirstlane(t >> 6);
    const int n  = blockIdx.x * 4 + ng;
    const float* mrow = m + n * 128;         // wave-uniform -> s_load
    const float* wrow = W_in + h * 128;      // 512 B contiguous per thread
    float acc = 0.f;
#pragma unroll
    for (int dq = 0; dq < 32; ++dq) {
        const float4 w  = *reinterpret_cast<const float4*>(wrow + dq * 4);
        const float4 mv = *reinterpret_cast<const float4*>(mrow + dq * 4);
        acc += w.x * mv.x + w.y * mv.y + w.z * mv.z + w.w * mv.w;
    }
    ab[n * 64 + h] = (acc + b_in[h]) * op_mask[0];
}

// k_T: grid=256. bid -> pt = bid&3 (16 p's), jt = bid>>2 (6 j's).
// Stage W_out[pt*16..+15][0..1023] into LDS with coalesced 4KB rows,
// then compute T from LDS (2-way-conflict-free via +4 pad) + s_load b.
__global__ __launch_bounds__(256) void k_T(const float* __restrict__ ab,
                                           const float* __restrict__ W_out,
                                           float* __restrict__ T) {
    const int t  = threadIdx.x;
    const int pt = blockIdx.x & 3;
    const int jt = blockIdx.x >> 2;
    __shared__ float Wsh[16][1028];          // 64.25 KB, pad 4 -> bank step 4

    // Stage: 16 rows x 4 KB, fully coalesced.
#pragma unroll
    for (int row = 0; row < 16; ++row) {
        const float4 v = *reinterpret_cast<const float4*>(
            W_out + (pt * 16 + row) * 1024 + t * 4);
        *reinterpret_cast<float4*>(&Wsh[row][t * 4]) = v;
    }
    __syncthreads();

    const int pl = t & 15;                   // p within tile
    const int xg = t >> 4;                   // 0..15
    const int p  = pt * 16 + pl;

#pragma unroll
    for (int xs = 0; xs < 2; ++xs) {
        const int x = xg * 2 + xs;
        float4 w[8];
#pragma unroll
        for (int yq = 0; yq < 8; ++yq)
            w[yq] = *reinterpret_cast<const float4*>(&Wsh[pl][x * 32 + yq * 4]);
#pragma unroll
        for (int jl = 0; jl < 6; ++jl) {
            const int j = jt * 6 + jl;
            const float* brow = ab + j * 64 + 32;   // wave-uniform -> s_load
            float s = 0.f;
#pragma unroll
            for (int yq = 0; yq < 8; ++yq) {
                s += brow[yq * 4 + 0] * w[yq].x + brow[yq * 4 + 1] * w[yq].y +
                     brow[yq * 4 + 2] * w[yq].z + brow[yq * 4 + 3] * w[yq].w;
            }
            T[j * 2048 + x * 64 + p] = s;
        }
    }
}

// out[i][j][p] = (sum_x a[i][x] * T[j][x*64+p] + b_out[p]) * op_norm   grid=576
// Block = 16i x 16j. Wave wv owns j = jt*16 + wv*4 + (lane>>4); p4=(lane&15)*4.
// launch_bounds(256,3): 3 waves/EU -> 3 blocks/CU co-resident, VGPR capped ~170.
__global__ __launch_bounds__(256, 3) void k_main3(const float* __restrict__ ab,
                                                  const float* __restrict__ T,
                                                  const float* __restrict__ b_out,
                                                  const float* __restrict__ op_norm,
                                                  float* __restrict__ out) {
    const int t    = threadIdx.x;
    const int lane = t & 63;
    const int wv   = __builtin_amdgcn_readfirstlane(t >> 6);
    const int jt   = blockIdx.x % 24;          // same-jt blocks share an XCD (24%8==0)
    const int it   = blockIdx.x / 24;
    const int jq   = lane >> 4;
    const int p4   = (lane & 15) * 4;
    const int j    = jt * 16 + wv * 4 + jq;
    const int i0   = it * 16;

    __shared__ float a_sh[16][32];             // 2 KB
    if (t < 128) {
        const int ii = t >> 3, xq8 = t & 7;
        *reinterpret_cast<float4*>(&a_sh[ii][xq8 * 4]) =
            *reinterpret_cast<const float4*>(ab + (i0 + ii) * 64 + xq8 * 4);
    }
    __syncthreads();

    const float4 bo  = *reinterpret_cast<const float4*>(b_out + p4);
    const float norm = op_norm[0];

    float4 acc[16];
#pragma unroll
    for (int i = 0; i < 16; ++i) acc[i] = bo;

    const float* Tj = T + j * 2048 + p4;

#pragma unroll 2
    for (int xq = 0; xq < 8; ++xq) {
        float4 t4[4];
#pragma unroll
        for (int s = 0; s < 4; ++s)
            t4[s] = *reinterpret_cast<const float4*>(Tj + (xq * 4 + s) * 64);
#pragma unroll
        for (int i = 0; i < 16; ++i) {
            const float4 av = *reinterpret_cast<const float4*>(&a_sh[i][xq * 4]); // LDS broadcast
            acc[i].x += av.x * t4[0].x + av.y * t4[1].x + av.z * t4[2].x + av.w * t4[3].x;
            acc[i].y += av.x * t4[0].y + av.y * t4[1].y + av.z * t4[2].y + av.w * t4[3].y;
            acc[i].z += av.x * t4[0].z + av.y * t4[1].z + av.z * t4[2].z + av.w * t4[3].z;
            acc[i].w += av.x * t4[0].w + av.y * t4[1].w + av.z * t4[2].w + av.w * t4[3].w;
        }
    }

#pragma unroll
    for (int i = 0; i < 16; ++i) {
        float4 r;
        r.x = acc[i].x * norm; r.y = acc[i].y * norm;
        r.z = acc[i].z * norm; r.w = acc[i].w * norm;
        *reinterpret_cast<float4*>(out + ((i0 + i) * NLOC + j) * 64 + p4) = r; // 1 KB/wave
    }
}

extern "C" void kernel_launch(void* const* d_in, const int* in_sizes, int n_in,
                              void* d_out, int out_size, void* d_ws, size_t ws_size,
                              hipStream_t stream) {
    const float* m       = (const float*)d_in[0];
    // d_in[1] = nlist (unused by the reference computation)
    const float* op_mask = (const float*)d_in[2];
    const float* op_norm = (const float*)d_in[3];
    const float* W_in    = (const float*)d_in[4];
    const float* b_in    = (const float*)d_in[5];
    const float* W_out   = (const float*)d_in[6];
    const float* b_out   = (const float*)d_in[7];
    float* out = (float*)d_out;

    float* ab = (float*)d_ws;                      // 384*64 f32
    float* T  = (float*)((char*)d_ws + 98304);     // 384*32*64 f32

    k_ab   <<<96,  256, 0, stream>>>(m, W_in, b_in, op_mask, ab);
    k_T    <<<256, 256, 0, stream>>>(ab, W_out, T);
    k_main3<<<576, 256, 0, stream>>>(ab, T, b_out, op_norm, out);
}

// Round 7
// 107.336 us; speedup vs baseline: 1.1204x; 1.1204x over previous
//
#include <hip/hip_runtime.h>

#define NLOC 384

// ws layout: ab[384*64] f32 at byte 0 (96 KB); T[384*32*64] f32 at byte 98304 (3 MB).
// T[j][x*64+p] = sum_y b[j][y] * W_out[p][x*32+y],  b[j][y] = ab[j*64+32+y]

// ab[n][h] = (sum_d m[n,d] * W_in[h,d] + b_in[h]) * op_mask    grid=96
__global__ __launch_bounds__(256) void k_ab(const float* __restrict__ m,
                                            const float* __restrict__ W_in,
                                            const float* __restrict__ b_in,
                                            const float* __restrict__ op_mask,
                                            float* __restrict__ ab) {
    const int t  = threadIdx.x;
    const int h  = t & 63;
    const int ng = __builtin_amdgcn_readfirstlane(t >> 6);
    const int n  = blockIdx.x * 4 + ng;
    const float* mrow = m + n * 128;         // wave-uniform -> s_load
    const float* wrow = W_in + h * 128;      // 512 B contiguous per thread
    float acc = 0.f;
#pragma unroll
    for (int dq = 0; dq < 32; ++dq) {
        const float4 w  = *reinterpret_cast<const float4*>(wrow + dq * 4);
        const float4 mv = *reinterpret_cast<const float4*>(mrow + dq * 4);
        acc += w.x * mv.x + w.y * mv.y + w.z * mv.z + w.w * mv.w;
    }
    ab[n * 64 + h] = (acc + b_in[h]) * op_mask[0];
}

// k_T2: grid=64 = 2 xp-halves x 32 j-tiles(12 j each).
// Thread owns (x, p4): keeps its 512 B W_out slice in registers (w[4][8] f4),
// then loops 12 j's: b[j] via wave-uniform s_loads, 128 FMA, 1 f4 store.
__global__ __launch_bounds__(256) void k_T2(const float* __restrict__ ab,
                                            const float* __restrict__ W_out,
                                            float* __restrict__ T) {
    const int t    = threadIdx.x;
    const int half = blockIdx.x & 1;
    const int jt   = blockIdx.x >> 1;
    const int xp0  = half * 1024 + t * 4;
    const int x    = xp0 >> 6;
    const int p0   = xp0 & 63;

    float4 w[4][8];                          // 128 VGPR: W_out[p0+c][32x .. 32x+31]
#pragma unroll
    for (int c = 0; c < 4; ++c)
#pragma unroll
        for (int yq = 0; yq < 8; ++yq)
            w[c][yq] = *reinterpret_cast<const float4*>(
                W_out + (p0 + c) * 1024 + x * 32 + yq * 4);

#pragma unroll
    for (int jl = 0; jl < 12; ++jl) {
        const int j = jt * 12 + jl;
        const float* brow = ab + j * 64 + 32;   // wave-uniform -> s_load broadcast
        float4 acc = {0.f, 0.f, 0.f, 0.f};
        float* accp = reinterpret_cast<float*>(&acc);
#pragma unroll
        for (int c = 0; c < 4; ++c) {
            float s = 0.f;
#pragma unroll
            for (int yq = 0; yq < 8; ++yq) {
                s += brow[yq * 4 + 0] * w[c][yq].x + brow[yq * 4 + 1] * w[c][yq].y +
                     brow[yq * 4 + 2] * w[c][yq].z + brow[yq * 4 + 3] * w[c][yq].w;
            }
            accp[c] = s;
        }
        *reinterpret_cast<float4*>(T + j * 2048 + xp0) = acc;  // 1 KB/wave coalesced
    }
}

// out[i][j][p] = (sum_x a[i][x] * T[j][x*64+p] + b_out[p]) * op_norm   grid=576
// Block = 16i x 16j. Wave wv owns j = jt*16 + wv*4 + (lane>>4); p4=(lane&15)*4.
// a-reads are wave-uniform scalar s_loads (R2's measured-best variant).
__global__ __launch_bounds__(256) void k_main2(const float* __restrict__ ab,
                                               const float* __restrict__ T,
                                               const float* __restrict__ b_out,
                                               const float* __restrict__ op_norm,
                                               float* __restrict__ out) {
    const int t    = threadIdx.x;
    const int lane = t & 63;
    const int wv   = __builtin_amdgcn_readfirstlane(t >> 6);
    const int jt   = blockIdx.x % 24;          // same-jt blocks share an XCD (24%8==0)
    const int it   = blockIdx.x / 24;
    const int jq   = lane >> 4;
    const int p4   = (lane & 15) * 4;
    const int j    = jt * 16 + wv * 4 + jq;
    const int i0   = it * 16;

    const float4 bo  = *reinterpret_cast<const float4*>(b_out + p4);
    const float norm = op_norm[0];

    float4 acc[16];
#pragma unroll
    for (int i = 0; i < 16; ++i) acc[i] = bo;

    const float* Tj   = T + j * 2048 + p4;
    const float* arow = ab + i0 * 64;           // wave-uniform -> s_load

#pragma unroll 4
    for (int x = 0; x < 32; ++x) {
        const float4 t4 = *reinterpret_cast<const float4*>(Tj + x * 64);
#pragma unroll
        for (int i = 0; i < 16; ++i) {
            const float a = arow[i * 64 + x];   // scalar (SGPR) operand
            acc[i].x += a * t4.x;
            acc[i].y += a * t4.y;
            acc[i].z += a * t4.z;
            acc[i].w += a * t4.w;
        }
    }

#pragma unroll
    for (int i = 0; i < 16; ++i) {
        float4 r;
        r.x = acc[i].x * norm; r.y = acc[i].y * norm;
        r.z = acc[i].z * norm; r.w = acc[i].w * norm;
        *reinterpret_cast<float4*>(out + ((i0 + i) * NLOC + j) * 64 + p4) = r; // 1 KB/wave
    }
}

extern "C" void kernel_launch(void* const* d_in, const int* in_sizes, int n_in,
                              void* d_out, int out_size, void* d_ws, size_t ws_size,
                              hipStream_t stream) {
    const float* m       = (const float*)d_in[0];
    // d_in[1] = nlist (unused by the reference computation)
    const float* op_mask = (const float*)d_in[2];
    const float* op_norm = (const float*)d_in[3];
    const float* W_in    = (const float*)d_in[4];
    const float* b_in    = (const float*)d_in[5];
    const float* W_out   = (const float*)d_in[6];
    const float* b_out   = (const float*)d_in[7];
    float* out = (float*)d_out;

    float* ab = (float*)d_ws;                      // 384*64 f32
    float* T  = (float*)((char*)d_ws + 98304);     // 384*32*64 f32

    k_ab   <<<96,  256, 0, stream>>>(m, W_in, b_in, op_mask, ab);
    k_T2   <<<64,  256, 0, stream>>>(ab, W_out, T);
    k_main2<<<576, 256, 0, stream>>>(ab, T, b_out, op_norm, out);
}